// Round 6
// baseline (327.786 us; speedup 1.0000x reference)
//
#include <hip/hip_runtime.h>
#include <hip/hip_bf16.h>
#include <stdint.h>

typedef __attribute__((ext_vector_type(4))) float f32x4;
typedef __attribute__((ext_vector_type(16))) float f32x16;
typedef __attribute__((ext_vector_type(8))) short short8;
typedef unsigned int u32;
typedef unsigned short ushort_t;

#define L_DIM 2048
#define B_DIM 32
#define D_DIM 512
#define M_DIM (L_DIM * B_DIM)       // 65536
#define N_DIM (3 * D_DIM)           // 1536
#define K_DIM D_DIM                 // 512
#define BD    (B_DIM * D_DIM)       // 16384
#define PLANE ((size_t)M_DIM * D_DIM)  // 33554432 elems per U plane
#define CHUNK 32
#define NCHUNK (L_DIM / CHUNK)      // 64

// ---------- helpers ----------
__device__ inline ushort_t f2bf(float f) {
    uint32_t u = __float_as_uint(f);
    u += 0x7FFFu + ((u >> 16) & 1u);   // RNE
    return (ushort_t)(u >> 16);
}
__device__ inline float b2f(ushort_t h) {
    return __uint_as_float(((uint32_t)h) << 16);
}
__device__ inline void gll16(const ushort_t* g, ushort_t* l) {
    __builtin_amdgcn_global_load_lds(
        (const __attribute__((address_space(1))) u32*)g,
        (__attribute__((address_space(3))) u32*)l,
        16, 0, 0);
}

// ---------- kernel 1: x (f32) -> xb (bf16) ----------
__global__ void k_convert_x(const float4* __restrict__ x, ushort4* __restrict__ xb) {
    int i = blockIdx.x * blockDim.x + threadIdx.x;
    int stride = gridDim.x * blockDim.x;
    const int n4 = M_DIM * D_DIM / 4;   // 8388608
    for (; i < n4; i += stride) {
        float4 v = x[i];
        ushort4 o;
        o.x = f2bf(v.x); o.y = f2bf(v.y); o.z = f2bf(v.z); o.w = f2bf(v.w);
        xb[i] = o;
    }
}

// ---------- kernel 2: weight (D,3D) f32 -> wt [N][K] bf16, gate-deinterleaved ----------
__global__ void k_prep_w(const float* __restrict__ w, ushort_t* __restrict__ wt) {
    int idx = blockIdx.x * blockDim.x + threadIdx.x;
    if (idx >= N_DIM * K_DIM) return;
    int k = idx & 511;
    int n = idx >> 9;
    int dcol = (n & 511) * 3 + (n >> 9);
    wt[idx] = f2bf(w[(size_t)k * N_DIM + dcol]);
}

// ---------- kernel 3: 256x256 GEMM, 4 waves, 32x32x16 MFMA, giant acc ----------
// Per-wave 128x128 output (acc f32x16[4][4] = 256 VGPR, 1 wave/SIMD).
// BK=32, 4 LDS buffers, stage t+3 during t, one vmcnt(16)+barrier per K-tile.
// LDS rows 64B; swizzle byte ^= (row&3)<<4 (read side), inverse on global src.
__global__ __launch_bounds__(256, 1) void k_gemm32(
    const ushort_t* __restrict__ Ag,   // [M,K] bf16
    const ushort_t* __restrict__ Wt,   // [N,K] bf16
    const float*    __restrict__ bias, // [2D]
    ushort_t*       __restrict__ U)    // 3 planes of [M,D] bf16
{
    __shared__ ushort_t As[4][256 * 32];   // 64 KB
    __shared__ ushort_t Bs[4][256 * 32];   // 64 KB
    const int tid  = threadIdx.x;
    const int lane = tid & 63;
    const int w    = tid >> 6;      // 0..3
    const int wm   = w >> 1, wn = w & 1;

    // XCD-chunked swizzle: 1536 blocks, 8 XCDs, 192/XCD; bx innermost (A L2 reuse)
    const int i   = blockIdx.x;
    const int nb  = (i & 7) * 192 + (i >> 3);
    const int bx  = nb % 6;
    const int by  = nb / 6;
    const int bn0 = bx * 256;
    const int bm0 = by * 256;

    // staging invariants: tile = 1024 chunks of 16B per matrix (4 chunks / 64B row),
    // round r covers rows r*64 + (tid>>2); source piece = (tid&3) ^ (row&3)
    const int rowoff = tid >> 2;
    const int psrc   = (tid & 3) ^ ((tid >> 2) & 3);
    const ushort_t* pA = Ag + (size_t)(bm0 + rowoff) * K_DIM + psrc * 8;
    const ushort_t* pB = Wt + (size_t)(bn0 + rowoff) * K_DIM + psrc * 8;

    f32x16 acc[4][4] = {};

#define STAGE(KT)                                                              \
    {                                                                          \
        ushort_t* Asn = &As[(KT) & 3][0];                                      \
        ushort_t* Bsn = &Bs[(KT) & 3][0];                                      \
        _Pragma("unroll")                                                      \
        for (int r = 0; r < 4; ++r)                                            \
            gll16(pA + (size_t)r * 64 * K_DIM + (KT) * 32,                     \
                  Asn + (r * 256 + w * 64) * 8);                               \
        _Pragma("unroll")                                                      \
        for (int r = 0; r < 4; ++r)                                            \
            gll16(pB + (size_t)r * 64 * K_DIM + (KT) * 32,                     \
                  Bsn + (r * 256 + w * 64) * 8);                               \
    }

#define TILE32(BUF, STG_KT, DO_STG, WN)                                        \
    {                                                                          \
        ushort_t* Asb = &As[BUF][0];                                           \
        ushort_t* Bsb = &Bs[BUF][0];                                           \
        if (DO_STG) STAGE(STG_KT);                                             \
        short8 af[4][2], bf[4][2];                                             \
        _Pragma("unroll")                                                      \
        for (int kk = 0; kk < 2; ++kk) {                                       \
            _Pragma("unroll")                                                  \
            for (int mm = 0; mm < 4; ++mm) {                                   \
                int rowA = wm * 128 + mm * 32 + (lane & 31);                   \
                int byte = rowA * 64 +                                         \
                    ((kk * 32 + (lane >> 5) * 16) ^ ((lane & 3) << 4));        \
                af[mm][kk] = *(const short8*)((const char*)Asb + byte);        \
            }                                                                  \
            _Pragma("unroll")                                                  \
            for (int nn = 0; nn < 4; ++nn) {                                   \
                int rowB = wn * 128 + nn * 32 + (lane & 31);                   \
                int byte = rowB * 64 +                                         \
                    ((kk * 32 + (lane >> 5) * 16) ^ ((lane & 3) << 4));        \
                bf[nn][kk] = *(const short8*)((const char*)Bsb + byte);        \
            }                                                                  \
        }                                                                      \
        __builtin_amdgcn_s_setprio(1);                                         \
        _Pragma("unroll")                                                      \
        for (int mm = 0; mm < 4; ++mm)                                         \
            _Pragma("unroll")                                                  \
            for (int nn = 0; nn < 4; ++nn)                                     \
                _Pragma("unroll")                                              \
                for (int kk = 0; kk < 2; ++kk)                                 \
                    acc[mm][nn] = __builtin_amdgcn_mfma_f32_32x32x16_bf16(     \
                        af[mm][kk], bf[nn][kk], acc[mm][nn], 0, 0, 0);         \
        __builtin_amdgcn_s_setprio(0);                                         \
        if ((WN) == 16)     asm volatile("s_waitcnt vmcnt(16)" ::: "memory");  \
        else if ((WN) == 8) asm volatile("s_waitcnt vmcnt(8)" ::: "memory");   \
        else if ((WN) == 0) asm volatile("s_waitcnt vmcnt(0)" ::: "memory");   \
        __builtin_amdgcn_s_barrier();                                          \
    }

    // prologue: stage K-tiles 0,1,2 (24 glls); wait for tile 0; barrier
    STAGE(0); STAGE(1); STAGE(2);
    asm volatile("s_waitcnt vmcnt(16)" ::: "memory");
    __builtin_amdgcn_s_barrier();

    // 16 K-tiles of BK=32; stage t+3 during t; counted vmcnt(16)
    TILE32(0,  3, 1, 16);   // kt=0
    TILE32(1,  4, 1, 16);   // kt=1
    TILE32(2,  5, 1, 16);   // kt=2
    TILE32(3,  6, 1, 16);   // kt=3
    TILE32(0,  7, 1, 16);   // kt=4
    TILE32(1,  8, 1, 16);   // kt=5
    TILE32(2,  9, 1, 16);   // kt=6
    TILE32(3, 10, 1, 16);   // kt=7
    TILE32(0, 11, 1, 16);   // kt=8
    TILE32(1, 12, 1, 16);   // kt=9
    TILE32(2, 13, 1, 16);   // kt=10
    TILE32(3, 14, 1, 16);   // kt=11
    TILE32(0, 15, 1, 16);   // kt=12 (last stage)
    TILE32(1,  0, 0,  8);   // kt=13 (wait tile 14)
    TILE32(2,  0, 0,  0);   // kt=14 (wait tile 15)
    TILE32(3,  0, 0, -1);   // kt=15

#undef TILE32
#undef STAGE

    // epilogue: 32x32 C/D layout col=lane&31, row=(reg&3)+8*(reg>>2)+4*(lane>>5)
    const int g = bn0 >> 9;                 // plane (bn0 multiple of 256; 512|plane)
    ushort_t* Up = U + (size_t)g * PLANE;
#pragma unroll
    for (int nn = 0; nn < 4; ++nn) {
        int col = (bn0 & 511) + wn * 128 + nn * 32 + (lane & 31);
        float ba = 0.f;
        if (g) ba = bias[(g - 1) * 512 + col];
#pragma unroll
        for (int mm = 0; mm < 4; ++mm) {
            int rbase = bm0 + wm * 128 + mm * 32 + 4 * (lane >> 5);
#pragma unroll
            for (int reg = 0; reg < 16; ++reg) {
                int row = rbase + (reg & 3) + 8 * (reg >> 2);
                Up[(size_t)row * D_DIM + col] = f2bf(acc[mm][nn][reg] + ba);
            }
        }
    }
}

// ---------- kernel 4: producer/consumer sequential scan (unchanged) ----------
__global__ __launch_bounds__(128) void k_scan(
    const ushort_t* __restrict__ U,    // 3 planes [t*32+b][d]
    const ushort_t* __restrict__ xb,   // [t*32+b][d]
    const float*    __restrict__ wc,   // weight_c [2D]
    const float*    __restrict__ cin,  // c_init [B,D]
    float*          __restrict__ out)  // h [L,B,D] f32, then c_last [B,D]
{
    __shared__ ushort_t ring[4][2][CHUNK][64];   // 32 KiB

    const int tid  = threadIdx.x;
    const int lane = tid & 63;
    const int wid  = tid >> 6;
    const int cb   = blockIdx.x * 64;            // chain base

    const int srow = lane >> 3;
    const int scol = (lane & 7) * 8;
    const ushort_t* s0 = U + cb + scol;
    const ushort_t* s1 = U + PLANE + cb + scol;
    const ushort_t* s2 = U + 2 * PLANE + cb + scol;
    const ushort_t* s3 = xb + cb + scol;

    const int chain = cb + lane;
    const int d     = chain & 511;
    float fw = 0.f, rw = 0.f, c = 0.f;
    if (wid == 1) { fw = wc[d]; rw = wc[512 + d]; c = cin[chain]; }
    float* ho = out + chain;

#define PRODUCE(CK, NB)                                                        \
    do {                                                                       \
        const size_t t0_ = (size_t)(CK) * CHUNK + srow;                        \
        _Pragma("unroll")                                                      \
        for (int q = 0; q < 4; ++q) {                                          \
            gll16(s0 + (t0_ + q * 8) * BD, &ring[0][NB][q * 8][0]);            \
            gll16(s1 + (t0_ + q * 8) * BD, &ring[1][NB][q * 8][0]);            \
            gll16(s2 + (t0_ + q * 8) * BD, &ring[2][NB][q * 8][0]);            \
            gll16(s3 + (t0_ + q * 8) * BD, &ring[3][NB][q * 8][0]);            \
        }                                                                      \
    } while (0)

#define LG(P, BUF, g0)                                                         \
    {                                                                          \
        _Pragma("unroll")                                                      \
        for (int s = 0; s < 8; ++s) {                                          \
            P##0[s] = ring[0][BUF][(g0) + s][lane];                            \
            P##1[s] = ring[1][BUF][(g0) + s][lane];                            \
            P##2[s] = ring[2][BUF][(g0) + s][lane];                            \
            P##x[s] = ring[3][BUF][(g0) + s][lane];                            \
        }                                                                      \
    }

#define CG(P, tb, g0)                                                          \
    {                                                                          \
        _Pragma("unroll")                                                      \
        for (int s = 0; s < 8; ++s) {                                          \
            float u0 = b2f(P##0[s]), u1 = b2f(P##1[s]);                        \
            float u2 = b2f(P##2[s]), xf = b2f(P##x[s]);                        \
            float f = __builtin_amdgcn_rcpf(1.f + __expf(-(u1 + c * fw)));     \
            float r = __builtin_amdgcn_rcpf(1.f + __expf(-(u2 + c * rw)));     \
            c = u0 + (c - u0) * f;                                             \
            ho[(size_t)((tb) + (g0) + s) * BD] = xf + (c - xf) * r;            \
        }                                                                      \
    }

    if (wid == 0) PRODUCE(0, 0);
    __syncthreads();

    for (int ck = 0; ck < NCHUNK; ++ck) {
        if (wid == 0) {
            if (ck + 1 < NCHUNK) {
                const int nb = (ck + 1) & 1;
                PRODUCE(ck + 1, nb);
            }
        } else {
            const int buf = ck & 1;
            const int tb  = ck * CHUNK;
            ushort_t A0[8], A1[8], A2[8], Ax[8];
            ushort_t B0[8], B1[8], B2[8], Bx[8];
            LG(A, buf, 0);
            LG(B, buf, 8);
            CG(A, tb, 0);
            LG(A, buf, 16);
            CG(B, tb, 8);
            LG(B, buf, 24);
            CG(A, tb, 16);
            CG(B, tb, 24);
        }
        __syncthreads();
    }

    if (wid == 1) out[(size_t)L_DIM * BD + chain] = c;
}

// ---------- launch ----------
extern "C" void kernel_launch(void* const* d_in, const int* in_sizes, int n_in,
                              void* d_out, int out_size, void* d_ws, size_t ws_size,
                              hipStream_t stream) {
    const float* x      = (const float*)d_in[0];
    const float* weight = (const float*)d_in[1];
    const float* wc     = (const float*)d_in[2];
    const float* bias   = (const float*)d_in[3];
    const float* cinit  = (const float*)d_in[4];
    float* out = (float*)d_out;

    // ws layout (bf16 elems): xb[33554432] | U0|U1|U2 [3*33554432] | wt[786432]
    ushort_t* ws = (ushort_t*)d_ws;
    ushort_t* xb = ws;
    ushort_t* U  = ws + PLANE;           // 3 contiguous planes
    ushort_t* wt = ws + 4 * PLANE;

    k_convert_x<<<4096, 256, 0, stream>>>((const float4*)x, (ushort4*)xb);
    k_prep_w<<<(N_DIM * K_DIM) / 256, 256, 0, stream>>>(weight, wt);
    k_gemm32<<<1536, 256, 0, stream>>>(xb, wt, bias, U);
    k_scan<<<BD / 64, 128, 0, stream>>>(U, xb, wc, cinit, out);
}